// Round 3
// baseline (299.687 us; speedup 1.0000x reference)
//
#include <hip/hip_runtime.h>
#include <hip/hip_bf16.h>

// Isokawa quaternion layer as bf16-MFMA GEMM:
//   out[b, n*4+oc] = sigmoid( sum_k x[b,k] * C[k, n*4+oc] - theta[n*4+oc] )
// B=131072 rows, K=256, N=256. Memory floor: 134 MB in + 134 MB out ~= 42 us.
//
// R5: barrier-free streaming waves (RMSNorm regime).
//  Evidence: three different block-coupled schedules (R2 burst, R3 reg-prefetch,
//  R4 async gload_lds + counted vmcnt) all tie at 85-90 us / ~50% duty cycle,
//  while barrier-free high-occupancy streaming kernels hit 4.9-6.3 TB/s on this
//  chip. So: eliminate ALL inter-wave coupling.
//   - No LDS, no barriers, no waitcnt choreography. Each wave independently
//     processes 16-row x 32-col tiles; x fragments loaded global->VGPR directly.
//   - Wave's 32-col coef slice lives in 64 VGPRs (breg) for the whole kernel.
//   - 8 col-waves of a block re-read the same x rows -> 8x read amplification
//     absorbed by same-CU L1/L2 (lines are touched by 2 consecutive instrs and
//     8 waves within a short window).
//   - VGPR <= 128 (__launch_bounds__(512,4)) -> 16 waves/CU, latency hidden by
//     TLP like the 6.3 TB/s copy kernel.
//   - MFMA operands swapped (breg as A) -> lane&15 = batch row, quad*4+reg = 4
//     consecutive n-cols -> float4 stores. rcp-based sigmoid.

typedef __bf16 bf16_t;
typedef bf16_t bf16x8 __attribute__((ext_vector_type(8)));
typedef float f32x4 __attribute__((ext_vector_type(4)));

#define B_TOTAL 131072
#define KDIM 256
#define NDIM 256
#define THREADS 512          // 8 waves; wave w owns cols [w*32, w*32+32)
#define ROWS_PER_BLOCK 256   // 16 tiles of 16 rows
#define TILES 16
#define GRID (B_TOTAL / ROWS_PER_BLOCK)   // 512 blocks = 2 resident per CU

// ---------------------------------------------------------------------------
// Kernel 1: build coefficient matrix in MFMA A-fragment order (bf16, in d_ws).
//   coef_frag[((nt*8 + ks)*64 + lane)*8 + j] = Bmat[k][col]
//     col = nt*16 + (lane&15),  k = ks*32 + (lane>>4)*8 + j
// Bmat[k][col]: col = n*4+oc, k = m*4+ic,
//   value = sign[oc][ic] * W[n, m, widx[oc][ic]]  (Hamilton, W on the left)
// ---------------------------------------------------------------------------
__global__ void coef_kernel(const float* __restrict__ W, bf16_t* __restrict__ coef) {
    const int widx[4][4] = {{0,1,2,3},{1,0,3,2},{2,3,0,1},{3,2,1,0}};
    const float sgn[4][4] = {{1.f,-1.f,-1.f,-1.f},
                             {1.f, 1.f,-1.f, 1.f},
                             {1.f, 1.f, 1.f,-1.f},
                             {1.f,-1.f, 1.f, 1.f}};
    int F = blockIdx.x * blockDim.x + threadIdx.x;   // 0..65535, one elem each
    int j    = F & 7;
    int lane = (F >> 3) & 63;
    int ks   = (F >> 9) & 7;
    int nt   = F >> 12;
    int col  = nt * 16 + (lane & 15);
    int k    = ks * 32 + (lane >> 4) * 8 + j;
    int n = col >> 2, oc = col & 3;
    int m = k >> 2,   ic = k & 3;
    coef[F] = (bf16_t)(sgn[oc][ic] * W[n * 256 + m * 4 + widx[oc][ic]]);
}

// ---------------------------------------------------------------------------
// Kernel 2: main GEMM, fully decoupled waves.
// MFMA 16x16x32 bf16 layouts (m89/m120-verified):
//   A-op: lane holds A[m=lane&15][k=(lane>>4)*8 + j]
//   B-op: lane holds B[k=(lane>>4)*8 + j][n=lane&15]
//   C/D : col=lane&15, row=(lane>>4)*4 + reg
// D' = mfma(coefFrag, xFrag): lane&15 = batch row, quad*4+reg = 4 consecutive
// n-cols -> float4 stores (verified R3/R4).
// x fragment for lane: row = l15, k = quad*8 + ks*32 + j  ->  two f32x4 loads
// per ks at byte offsets ks*128 + {0,16} off (row*1024 + quad*32); lo/hi pairs
// of one ks cover a full 128B line across the wave.
// ---------------------------------------------------------------------------
__global__ __launch_bounds__(THREADS, 4)
void main_kernel(const float* __restrict__ x, const bf16x8* __restrict__ coef,
                 const float* __restrict__ theta, float* __restrict__ out) {
    const int tid  = threadIdx.x;
    const int wave = tid >> 6, lane = tid & 63;
    const int l15  = lane & 15, quad = lane >> 4;

    // --- this wave's 32-col coef slice, register-resident for the whole kernel
    bf16x8 breg[2][8];
#pragma unroll
    for (int ct = 0; ct < 2; ct++)
#pragma unroll
        for (int ks = 0; ks < 8; ks++)
            breg[ct][ks] = coef[((wave * 2 + ct) * 8 + ks) * 64 + lane];

    f32x4 th4[2];
#pragma unroll
    for (int ct = 0; ct < 2; ct++)
        th4[ct] = *(const f32x4*)&theta[wave * 32 + ct * 16 + quad * 4];

    const long row_base = (long)blockIdx.x * ROWS_PER_BLOCK;

#pragma unroll 1
    for (int t = 0; t < TILES; t++) {
        const long row = row_base + t * 16 + l15;
        const float* xr = x + row * KDIM + quad * 8;   // this lane's k-origin

        f32x4 acc[2];
        acc[0] = (f32x4)(0.f);
        acc[1] = (f32x4)(0.f);

        // K-loop: direct global->reg fragments (immediate offsets), cvt, MFMA
#pragma unroll
        for (int ks = 0; ks < 8; ks++) {
            f32x4 lo = *(const f32x4*)(xr + ks * 32);
            f32x4 hi = *(const f32x4*)(xr + ks * 32 + 4);
            bf16x8 af;
            af[0] = (bf16_t)lo[0]; af[1] = (bf16_t)lo[1];
            af[2] = (bf16_t)lo[2]; af[3] = (bf16_t)lo[3];
            af[4] = (bf16_t)hi[0]; af[5] = (bf16_t)hi[1];
            af[6] = (bf16_t)hi[2]; af[7] = (bf16_t)hi[3];
            acc[0] = __builtin_amdgcn_mfma_f32_16x16x32_bf16(
                breg[0][ks], af, acc[0], 0, 0, 0);
            acc[1] = __builtin_amdgcn_mfma_f32_16x16x32_bf16(
                breg[1][ks], af, acc[1], 0, 0, 0);
        }

        // epilogue: bias + sigmoid (fast rcp), float4 stores
        float* orow = out + row * NDIM + wave * 32 + quad * 4;
#pragma unroll
        for (int ct = 0; ct < 2; ct++) {
            f32x4 y;
#pragma unroll
            for (int j = 0; j < 4; j++) {
                float s = acc[ct][j] - th4[ct][j];
                y[j] = __builtin_amdgcn_rcpf(1.0f + __expf(-s));
            }
            *(f32x4*)(orow + ct * 16) = y;
        }
    }
}

extern "C" void kernel_launch(void* const* d_in, const int* in_sizes, int n_in,
                              void* d_out, int out_size, void* d_ws, size_t ws_size,
                              hipStream_t stream) {
    const float* x     = (const float*)d_in[0];   // (131072, 64, 4) fp32
    const float* W     = (const float*)d_in[1];   // (64, 64, 4) fp32
    const float* theta = (const float*)d_in[2];   // (64, 4) fp32
    float* out = (float*)d_out;                   // (131072, 64, 4) fp32
    bf16_t* coef = (bf16_t*)d_ws;                 // 65536 bf16 = 128 KB

    if (ws_size < 65536 * sizeof(bf16_t)) return;

    coef_kernel<<<256, 256, 0, stream>>>(W, coef);
    main_kernel<<<GRID, THREADS, 0, stream>>>(
        x, (const bf16x8*)coef, theta, out);
}